// Round 7
// baseline (292.242 us; speedup 1.0000x reference)
//
#include <hip/hip_runtime.h>

typedef short v8s __attribute__((ext_vector_type(8)));
typedef float v4f __attribute__((ext_vector_type(4)));

#define BH 16384             // B*H
#define TBH 33554432         // T*B*H
#define SEG2 32              // segments over T
#define SEGT2 64             // timesteps per segment (2048/32)
#define SCAN_TILE 128        // (fallback scan) timesteps per LDS tile
#define NTILE 16             // 2048 / 128

__device__ __forceinline__ ushort f2bf(float f) {
  // round-to-nearest-even fp32 -> bf16 (inputs finite, no NaN handling needed)
  uint u = __float_as_uint(f);
  u += 0x7FFF + ((u >> 16) & 1);
  return (ushort)(u >> 16);
}

// pack 2 fp32 -> 2 bf16 in one uint via the HW pack-convert (RTNE, matches f2bf)
__device__ __forceinline__ uint pkbf2(float a, float b) {
  uint r;
  asm("v_cvt_pk_bf16_f32 %0, %1, %2" : "=v"(r) : "v"(a), "v"(b));
  return r;
}

union frag_u { uint u[4]; v8s s; };

// ---------------- Phase 0: W fp32 -> bf16, pre-swizzled into DMA-linear layout --------
// (r5 version, proven with gemm v3.) Wbf[kc][row][sp] 16B slots; slot sp holds logical
// k-slot sp^(row&7): W[row][kc*64 + (sp^(row&7))*8 .. +7].
__global__ __launch_bounds__(256) void indrnn_w2bf(
    const float* __restrict__ W, ushort* __restrict__ Wbf)
{
  const int g   = blockIdx.x * 256 + threadIdx.x;   // 8192 slots total
  const int kc  = g >> 11;
  const int rem = g & 2047;
  const int row = rem >> 3;
  const int sp  = rem & 7;
  const int slog = sp ^ (row & 7);
  const float* src = W + row * 256 + kc * 64 + slog * 8;
  const float4 f0 = *(const float4*)src;
  const float4 f1 = *(const float4*)(src + 4);
  uint4 o;
  o.x = pkbf2(f0.x, f0.y); o.y = pkbf2(f0.z, f0.w);
  o.z = pkbf2(f1.x, f1.y); o.w = pkbf2(f1.z, f1.w);
  *(uint4*)(Wbf + (size_t)g * 8) = o;
}

// ---------------- Phase 1: xW[m,h] = sum_i x[m,i] * W[h,i], bf16 MFMA ----------------
// (r5 v3, best measured total: DMA-staged, VALU-free staging, 3 blocks/CU. FROZEN.)
__global__ __launch_bounds__(256, 3) void indrnn_gemm(
    const float* __restrict__ A,
    const ushort* __restrict__ Wbf,
    ushort* __restrict__ C)
{
  __shared__ __align__(16) float  Af[4096];    // 64 rows x 16 slots x 4 fp32 = 16 KB
  __shared__ __align__(16) ushort Bs[16384];   // 256 rows x 8 slots x 8 bf16 = 32 KB

  const int tid   = threadIdx.x;
  const int lane  = tid & 63;
  const int wn    = tid >> 6;      // 0..3 -> 64-col slice of H
  const int l15   = lane & 15;
  const int lhi   = lane >> 4;     // 0..3
  const int m0    = blockIdx.x * 64;
  const int bflat = tid & 192;     // wave base slot within block round

  v4f acc[4][4] = {};

  for (int kc = 0; kc < 4; ++kc) {
    if (kc) __syncthreads();       // all waves done reading previous tiles

    // A tile DMA: 64 rows x 64 k fp32, source pre-swizzled so LDS is XOR-laid-out
    #pragma unroll
    for (int j = 0; j < 4; ++j) {
      const int bf_ = j * 256 + bflat;          // wave-uniform LDS slot base
      const int fl  = bf_ + lane;
      const int row = fl >> 4;
      const int sl  = fl & 15;
      const float* src = A + ((size_t)(m0 + row) << 8) + kc * 64 + ((sl ^ (row & 7)) << 2);
      __builtin_amdgcn_global_load_lds(src, &Af[bf_ << 2], 16, 0, 0);
    }
    // W tile DMA: 256 rows x 64 k bf16, fully linear from pre-swizzled Wbf
    #pragma unroll
    for (int j = 0; j < 8; ++j) {
      const int bf_ = j * 256 + bflat;
      const int fl  = bf_ + lane;
      __builtin_amdgcn_global_load_lds(
          (const float*)(Wbf + (size_t)kc * 16384 + (size_t)fl * 8),
          (float*)(Bs + (size_t)bf_ * 8), 16, 0, 0);
    }
    asm volatile("s_waitcnt vmcnt(0)" ::: "memory");
    __syncthreads();

    #pragma unroll
    for (int kk = 0; kk < 2; ++kk) {
      // B frags: one swizzled 16B slot each (bf16 direct)
      v8s bfr[4];
      #pragma unroll
      for (int nt = 0; nt < 4; ++nt) {
        const int row = wn * 64 + nt * 16 + l15;
        const int sp  = (kk * 4 + lhi) ^ (row & 7);
        bfr[nt] = *(const v8s*)((const char*)Bs + row * 128 + sp * 16);
      }
      // A frags: two swizzled fp32 slots -> cvt_pk -> bf16 frag, then 4 MFMAs
      #pragma unroll
      for (int mt = 0; mt < 4; ++mt) {
        const int row = mt * 16 + l15;
        const int s0  = kk * 8 + lhi * 2;
        const char* base = (const char*)Af + row * 256;
        const float4 lo = *(const float4*)(base + ((s0 ^ (row & 7)) << 4));
        const float4 hi = *(const float4*)(base + (((s0 + 1) ^ (row & 7)) << 4));
        frag_u t;
        t.u[0] = pkbf2(lo.x, lo.y); t.u[1] = pkbf2(lo.z, lo.w);
        t.u[2] = pkbf2(hi.x, hi.y); t.u[3] = pkbf2(hi.z, hi.w);
        #pragma unroll
        for (int nt = 0; nt < 4; ++nt)
          acc[mt][nt] = __builtin_amdgcn_mfma_f32_16x16x32_bf16(t.s, bfr[nt], acc[mt][nt], 0, 0, 0);
      }
    }
  }

  // epilogue: C/D layout col=lane&15, row=(lane>>4)*4+reg
  #pragma unroll
  for (int mt = 0; mt < 4; ++mt) {
    #pragma unroll
    for (int nt = 0; nt < 4; ++nt) {
      #pragma unroll
      for (int r = 0; r < 4; ++r) {
        int row = m0 + mt * 16 + lhi * 4 + r;
        int col = wn * 64 + nt * 16 + l15;
        C[((size_t)row << 8) + col] = f2bf(acc[mt][nt][r]);
      }
    }
  }
}

// ---------------- Phase 2a: per-segment transfer functions (v2) ----------------
// IndRNN step f(h)=max(0, x + w*h) preserves the family F(h)=clamp(p*h+a, lo, hi).
// v2: SEG=32 (64 steps), 2 channels/thread (uint loads), whole segment buffered in
// VGPRs so all 64 loads are in flight at once (in-flight bytes/CU ~4 KB -> BW-class).
__global__ __launch_bounds__(256, 4) void indrnn_seg(
    const ushort* __restrict__ xw,
    const float* __restrict__ w_hh,
    float4* __restrict__ fn)
{
  const int seg = blockIdx.x >> 5;                        // 0..31
  const int cp  = (blockIdx.x & 31) * 256 + threadIdx.x;  // channel pair 0..8191
  const int ch  = cp * 2;
  const float w0 = w_hh[ch & 255];
  const float w1 = w_hh[(ch + 1) & 255];
  const ushort* px = xw + (size_t)seg * SEGT2 * BH + ch;

  uint buf[SEGT2];
  #pragma unroll
  for (int t = 0; t < SEGT2; ++t)
    buf[t] = *(const uint*)(px + (size_t)t * BH);

  float p0 = 1.f, a0 = 0.f, lo0 = -3.402823466e38f, hi0 = 3.402823466e38f;
  float p1 = 1.f, a1 = 0.f, lo1 = -3.402823466e38f, hi1 = 3.402823466e38f;
  #pragma unroll
  for (int t = 0; t < SEGT2; ++t) {
    const float x0 = __uint_as_float(buf[t] << 16);
    const float x1 = __uint_as_float(buf[t] & 0xFFFF0000u);
    float A, B;
    A = fmaf(w0, lo0, x0); B = fmaf(w0, hi0, x0);
    lo0 = fmaxf(0.f, fminf(A, B)); hi0 = fmaxf(0.f, fmaxf(A, B));
    a0 = fmaf(w0, a0, x0); p0 *= w0;
    A = fmaf(w1, lo1, x1); B = fmaf(w1, hi1, x1);
    lo1 = fmaxf(0.f, fminf(A, B)); hi1 = fmaxf(0.f, fmaxf(A, B));
    a1 = fmaf(w1, a1, x1); p1 *= w1;
  }
  fn[(size_t)seg * BH + ch]     = make_float4(p0, a0, lo0, hi0);
  fn[(size_t)seg * BH + ch + 1] = make_float4(p1, a1, lo1, hi1);
}

// ---------------- Phase 2b: prefix-compose h_in, then re-scan + store (v2) ----------
// xw loads issued FIRST (long pole, in flight), then <=31 L2-hot clamp-affine
// compositions, then compute + float2 stores.
__global__ __launch_bounds__(256, 4) void indrnn_fix(
    const ushort* __restrict__ xw,
    const float* __restrict__ h0,
    const float* __restrict__ w_hh,
    const float4* __restrict__ fn,
    float* __restrict__ out)
{
  const int seg = blockIdx.x >> 5;
  const int cp  = (blockIdx.x & 31) * 256 + threadIdx.x;
  const int ch  = cp * 2;
  const float w0 = w_hh[ch & 255];
  const float w1 = w_hh[(ch + 1) & 255];

  const ushort* px = xw + (size_t)seg * SEGT2 * BH + ch;
  float*        po = out + (size_t)seg * SEGT2 * BH + ch;

  // issue all 64 segment loads before the prefix chain (hide HBM/L3 latency under it)
  uint buf[SEGT2];
  #pragma unroll
  for (int t = 0; t < SEGT2; ++t)
    buf[t] = *(const uint*)(px + (size_t)t * BH);

  // exact segment-entry state via <=31 clamp-affine compositions (L2-hot fn)
  float h0v = h0[ch], h1v = h0[ch + 1];
  for (int s = 0; s < seg; ++s) {
    const float4 F0 = fn[(size_t)s * BH + ch];
    const float4 F1 = fn[(size_t)s * BH + ch + 1];
    h0v = fminf(fmaxf(fmaf(F0.x, h0v, F0.y), F0.z), F0.w);
    h1v = fminf(fmaxf(fmaf(F1.x, h1v, F1.y), F1.z), F1.w);
  }

  #pragma unroll
  for (int t = 0; t < SEGT2; ++t) {
    const float x0 = __uint_as_float(buf[t] << 16);
    const float x1 = __uint_as_float(buf[t] & 0xFFFF0000u);
    h0v = fmaxf(fmaf(h0v, w0, x0), 0.f);
    h1v = fmaxf(fmaf(h1v, w1, x1), 0.f);
    *(float2*)(po + (size_t)t * BH) = make_float2(h0v, h1v);
  }

  if (seg == SEG2 - 1) {
    out[(size_t)TBH + ch]     = h0v;
    out[(size_t)TBH + ch + 1] = h1v;
  }
}

// ---------------- Fallbacks (workspace-tight path): r0 gemm + r3 scan ----------------
__global__ __launch_bounds__(512) void indrnn_gemm_fb(
    const float* __restrict__ A,
    const float* __restrict__ W,
    ushort* __restrict__ C)
{
  __shared__ ushort As[128 * 72];
  __shared__ ushort Bs[256 * 72];

  const int tid  = threadIdx.x;
  const int lane = tid & 63;
  const int wid  = tid >> 6;
  const int wm   = wid >> 2;
  const int wn   = wid & 3;
  const int m0   = blockIdx.x * 128;
  const int l15 = lane & 15;
  const int lhi = lane >> 4;

  v4f acc[4][4] = {};

  for (int kc = 0; kc < 4; ++kc) {
    #pragma unroll
    for (int j = 0; j < 4; ++j) {
      int f    = j * 512 + tid;
      int row  = f >> 4;
      int colf = f & 15;
      const float4 a4 = *(const float4*)(A + ((size_t)(m0 + row) << 8) + kc * 64 + colf * 4);
      ushort4 b4 = make_ushort4(f2bf(a4.x), f2bf(a4.y), f2bf(a4.z), f2bf(a4.w));
      *(ushort4*)(As + row * 72 + colf * 4) = b4;
    }
    #pragma unroll
    for (int j = 0; j < 8; ++j) {
      int f    = j * 512 + tid;
      int row  = f >> 4;
      int colf = f & 15;
      const float4 a4 = *(const float4*)(W + ((size_t)row << 8) + kc * 64 + colf * 4);
      ushort4 b4 = make_ushort4(f2bf(a4.x), f2bf(a4.y), f2bf(a4.z), f2bf(a4.w));
      *(ushort4*)(Bs + row * 72 + colf * 4) = b4;
    }
    __syncthreads();

    #pragma unroll
    for (int kk = 0; kk < 2; ++kk) {
      const int koff = kk * 32 + lhi * 8;
      v8s af[4], bf[4];
      #pragma unroll
      for (int mt = 0; mt < 4; ++mt)
        af[mt] = *(const v8s*)(As + (wm * 64 + mt * 16 + l15) * 72 + koff);
      #pragma unroll
      for (int nt = 0; nt < 4; ++nt)
        bf[nt] = *(const v8s*)(Bs + (wn * 64 + nt * 16 + l15) * 72 + koff);
      #pragma unroll
      for (int mt = 0; mt < 4; ++mt)
        #pragma unroll
        for (int nt = 0; nt < 4; ++nt)
          acc[mt][nt] = __builtin_amdgcn_mfma_f32_16x16x32_bf16(af[mt], bf[nt], acc[mt][nt], 0, 0, 0);
    }
    __syncthreads();
  }

  #pragma unroll
  for (int mt = 0; mt < 4; ++mt)
    #pragma unroll
    for (int nt = 0; nt < 4; ++nt)
      #pragma unroll
      for (int r = 0; r < 4; ++r) {
        int row = m0 + wm * 64 + mt * 16 + lhi * 4 + r;
        int col = wn * 64 + nt * 16 + l15;
        C[((size_t)row << 8) + col] = f2bf(acc[mt][nt][r]);
      }
}

__global__ __launch_bounds__(128) void indrnn_scan(
    const ushort* __restrict__ xw,
    const float* __restrict__ h0,
    const float* __restrict__ w_hh,
    float* __restrict__ out)
{
  __shared__ __align__(16) ushort tile[3][SCAN_TILE * 64];

  const int lane = threadIdx.x & 63;
  const int wv   = threadIdx.x >> 6;
  const int ch0  = blockIdx.x * 64;
  const int ch   = ch0 + lane;

  const size_t psrc0 = (size_t)(lane >> 3) * BH + (size_t)ch0 + ((lane & 7) << 3);

  auto stage = [&](int ti) {
    const ushort* src = xw + (size_t)ti * SCAN_TILE * BH + psrc0;
    ushort* dst = &tile[ti % 3][0];
    #pragma unroll
    for (int j = 0; j < 16; ++j) {
      __builtin_amdgcn_global_load_lds(
          (const float*)(src + (size_t)j * 8 * BH),
          (float*)(dst + j * 512), 16, 0, 0);
    }
  };

  float h = 0.0f, w = 0.0f;
  if (wv == 0) {
    h = h0[ch];
    w = w_hh[ch & 255];
  } else {
    stage(0);
    stage(1);
    asm volatile("s_waitcnt vmcnt(16)" ::: "memory");
  }
  asm volatile("" ::: "memory");
  __builtin_amdgcn_s_barrier();
  __builtin_amdgcn_sched_barrier(0);

  for (int i = 0; i < NTILE; ++i) {
    if (wv == 0) {
      const ushort* tp = &tile[i % 3][lane];
      float* po = out + (size_t)i * SCAN_TILE * BH + ch;
      #pragma unroll
      for (int t = 0; t < SCAN_TILE; t += 16) {
        ushort v[16];
        #pragma unroll
        for (int j = 0; j < 16; ++j) v[j] = tp[(t + j) * 64];
        #pragma unroll
        for (int j = 0; j < 16; ++j) {
          float xv = __uint_as_float((uint)v[j] << 16);
          h = fmaxf(fmaf(h, w, xv), 0.0f);
          po[(size_t)(t + j) * BH] = h;
        }
      }
    } else {
      if (i + 2 < NTILE) {
        stage(i + 2);
        asm volatile("s_waitcnt vmcnt(16)" ::: "memory");
      } else {
        asm volatile("s_waitcnt vmcnt(0)" ::: "memory");
      }
    }
    asm volatile("" ::: "memory");
    __builtin_amdgcn_s_barrier();
    __builtin_amdgcn_sched_barrier(0);
  }

  if (wv == 0) out[(size_t)TBH + ch] = h;
}

extern "C" void kernel_launch(void* const* d_in, const int* in_sizes, int n_in,
                              void* d_out, int out_size, void* d_ws, size_t ws_size,
                              hipStream_t stream) {
  const float* x    = (const float*)d_in[0];   // [2048, 64, 256]
  const float* h0   = (const float*)d_in[1];   // [1, 64, 256]
  const float* W_ih = (const float*)d_in[2];   // [256, 256]
  const float* w_hh = (const float*)d_in[3];   // [256]
  float* out = (float*)d_out;                  // [T,B,H] ++ [1,B,H]
  ushort* xw = (ushort*)d_ws;                  // bf16 intermediate, 64 MiB

  const size_t off_fn = 64ull << 20;                                   // 64 MiB
  const size_t off_wb = off_fn + (size_t)SEG2 * BH * sizeof(float4);   // +8 MiB
  const size_t need   = off_wb + 131072;                               // +128 KiB

  if (ws_size >= need) {
    float4* fn  = (float4*)((char*)d_ws + off_fn);
    ushort* wbf = (ushort*)((char*)d_ws + off_wb);
    indrnn_w2bf<<<dim3(32),   dim3(256), 0, stream>>>(W_ih, wbf);
    indrnn_gemm<<<dim3(2048), dim3(256), 0, stream>>>(x, wbf, xw);
    indrnn_seg <<<dim3(1024), dim3(256), 0, stream>>>(xw, w_hh, fn);
    indrnn_fix <<<dim3(1024), dim3(256), 0, stream>>>(xw, h0, w_hh, fn, out);
  } else {
    indrnn_gemm_fb<<<dim3(1024), dim3(512), 0, stream>>>(x, W_ih, xw);
    indrnn_scan<<<dim3(256), dim3(128), 0, stream>>>(xw, h0, w_hh, out);
  }
}